// Round 1
// baseline (33991.055 us; speedup 1.0000x reference)
//
#include <hip/hip_runtime.h>
#include <hip/hip_bf16.h>

// CfC recurrent net. B=64,T=512,I=256,H=512,BU=1024.
// Persistent-kernel design: 256 wgs x 64 threads (1 wave each), 3 device-wide
// flag barriers per timestep. bf16 MFMA (16x16x32), fp32 accumulate/epilogue.

#define Bb  64
#define Tt  512
#define Ii  256
#define Hh  512
#define BUu 1024
#define KC  768   // I+H

typedef __attribute__((ext_vector_type(8))) short bf16x8;   // 8 bf16 = 4 VGPR
typedef __attribute__((ext_vector_type(4))) float f32x4;

// ---- workspace layout (bytes) ----
#define OFF_WB1   0u         // bf16 [1024][768]
#define OFF_WB2   1572864u   // bf16 [1024][1024]
#define OFF_WHD   3670016u   // bf16 [1536][1024], row c = 3*i+head (head2 = wta+wtb)
#define OFF_Z1    6815744u   // bf16 [64][1024]
#define OFF_Z2    6946816u   // bf16 [64][1024]
#define OFF_H     7077888u   // bf16 [64][512]
#define OFF_FLAGS 7143424u   // uint [256]
// total ~6.82 MB

__device__ __forceinline__ short f2bf(float f) {   // fp32 -> bf16 RNE
  unsigned u = __builtin_bit_cast(unsigned, f);
  u += 0x7FFFu + ((u >> 16) & 1u);
  return (short)(u >> 16);
}
__device__ __forceinline__ float fast_tanh(float u) {
  float e = __expf(2.0f * u);
  return (e - 1.0f) / (e + 1.0f);
}
__device__ __forceinline__ float fast_sig(float x) {
  return 1.0f / (1.0f + __expf(-x));
}
__device__ __forceinline__ float lecun_act(float u) {
  return 1.7159f * fast_tanh(0.666f * u);
}

// device-wide barrier: flag per wg (release), all lanes poll 4 flags each.
__device__ __forceinline__ void gbar(unsigned* flags, int wg, int lane, unsigned g) {
  __threadfence();  // release: publish prior global stores (cross-XCD)
  if (lane == 0)
    __hip_atomic_store(flags + wg, g, __ATOMIC_RELEASE, __HIP_MEMORY_SCOPE_AGENT);
  const unsigned* fp = flags + (lane << 2);
  for (;;) {
    unsigned a = __hip_atomic_load(fp + 0, __ATOMIC_RELAXED, __HIP_MEMORY_SCOPE_AGENT);
    unsigned b = __hip_atomic_load(fp + 1, __ATOMIC_RELAXED, __HIP_MEMORY_SCOPE_AGENT);
    unsigned c = __hip_atomic_load(fp + 2, __ATOMIC_RELAXED, __HIP_MEMORY_SCOPE_AGENT);
    unsigned d = __hip_atomic_load(fp + 3, __ATOMIC_RELAXED, __HIP_MEMORY_SCOPE_AGENT);
    if (__all((int)((a >= g) && (b >= g) && (c >= g) && (d >= g)))) break;
    __builtin_amdgcn_s_sleep(2);
  }
  __threadfence();  // acquire: invalidate stale cached lines before data reads
}

// ---- prep: weight conversion to bf16, fused head matrix, zero h/flags ----
__global__ void cfc_prep(const float* __restrict__ wb1, const float* __restrict__ wb2,
                         const float* __restrict__ wff1, const float* __restrict__ wff2,
                         const float* __restrict__ wta, const float* __restrict__ wtb,
                         unsigned char* __restrict__ ws) {
  const unsigned N1 = 1024u * 768u;
  const unsigned N2 = 1024u * 1024u;
  const unsigned N3 = 1536u * 1024u;
  const unsigned NH = 64u * 512u;
  const unsigned NF = 256u;
  unsigned idx = blockIdx.x * blockDim.x + threadIdx.x;
  short* Wb1 = (short*)(ws + OFF_WB1);
  short* Wb2 = (short*)(ws + OFF_WB2);
  short* Whd = (short*)(ws + OFF_WHD);
  short* Hbuf = (short*)(ws + OFF_H);
  unsigned* flags = (unsigned*)(ws + OFF_FLAGS);
  if (idx < N1) { Wb1[idx] = f2bf(wb1[idx]); return; }
  idx -= N1;
  if (idx < N2) { Wb2[idx] = f2bf(wb2[idx]); return; }
  idx -= N2;
  if (idx < N3) {
    unsigned c = idx >> 10, k = idx & 1023u;
    unsigned i = c / 3u, hd = c % 3u;
    float v = (hd == 0u) ? wff1[i * 1024u + k]
            : (hd == 1u) ? wff2[i * 1024u + k]
                         : (wta[i * 1024u + k] + wtb[i * 1024u + k]);
    Whd[idx] = f2bf(v);
    return;
  }
  idx -= N3;
  if (idx < NH) { Hbuf[idx] = 0; return; }
  idx -= NH;
  if (idx < NF) { flags[idx] = 0u; }
}

// ---- persistent recurrent kernel ----
__global__ __launch_bounds__(64) void cfc_run(
    const float* __restrict__ x,
    const float* __restrict__ bb1, const float* __restrict__ bb2,
    const float* __restrict__ bff1, const float* __restrict__ bff2,
    const float* __restrict__ bta, const float* __restrict__ btb,
    unsigned char* __restrict__ ws, float* __restrict__ out) {
  // LDS: WL1 16x1536B [0,24576) | WL2 16x2048B [24576,57344) | S3 stage 3KB [57344,60416)
  __shared__ __align__(16) char smem[60416];
  const int wg = blockIdx.x;     // 0..255
  const int lane = threadIdx.x;  // 0..63
  const short* Wb1 = (const short*)(ws + OFF_WB1);
  const short* Wb2 = (const short*)(ws + OFF_WB2);
  const short* Whd = (const short*)(ws + OFF_WHD);
  short* z1 = (short*)(ws + OFF_Z1);
  short* z2 = (short*)(ws + OFF_Z2);
  short* hb = (short*)(ws + OFF_H);
  unsigned* flags = (unsigned*)(ws + OFF_FLAGS);

  // S1/S2 job: (bt 0..3)=16 batch rows, (nt 0..63)=16 cols.  wg%8==nt%8 -> all
  // batch tiles of a column slice land on the same XCD (weight L2 locality).
  const int bt = wg >> 6, nt = wg & 63;
  const int b0 = bt << 4, n0 = nt << 4;

  const int row16 = lane & 15;       // A-row / B-col / D-col index of this lane
  const int kg = lane >> 4;          // k-group 0..3 (8 bf16 each)
  const int kg16 = kg << 4;          // byte offset of k-group
  const int swzm = (row16 & 7) << 4; // LDS row xor-swizzle (guide §6 G4)
  const int rbase = kg << 2;         // D rows = rbase..rbase+3

  // preload this wg's Wb1/Wb2 row slices into LDS (xor-swizzled rows)
  for (int c = lane; c < 16 * 96; c += 64) {
    int r = c / 96, kb = (c % 96) << 4;
    *(bf16x8*)(smem + r * 1536 + (kb ^ ((r & 7) << 4))) =
        *(const bf16x8*)(Wb1 + (size_t)(n0 + r) * KC + (kb >> 1));
  }
  for (int c = lane; c < 16 * 128; c += 64) {
    int r = c / 128, kb = (c % 128) << 4;
    *(bf16x8*)(smem + 24576 + r * 2048 + (kb ^ ((r & 7) << 4))) =
        *(const bf16x8*)(Wb2 + (size_t)(n0 + r) * BUu + (kb >> 1));
  }
  __syncthreads();

  // hoisted per-lane constants
  const float bias1 = bb1[n0 + row16];
  const float bias2 = bb2[n0 + row16];
  const short* hrow = hb + (b0 + row16) * Hh;
  const float* xbase = x + (size_t)(b0 + row16) * Tt * Ii;
  const short* z1row = z1 + (b0 + row16) * BUu;
  // S3 job (wgs 0..127): (bt3 0..3)=16 rows, (it3 0..31)=16 i's (48 cols)
  const int bt3 = (wg >> 5) & 3, it3 = wg & 31;
  const int b03 = bt3 << 4;
  const int ig = (it3 << 4) + row16;
  const short* z2row = z2 + (b03 + row16) * BUu;
  const short* wh0 = Whd + (size_t)(it3 * 48 + 0 + row16) * BUu;
  const short* wh1 = Whd + (size_t)(it3 * 48 + 16 + row16) * BUu;
  const short* wh2 = Whd + (size_t)(it3 * 48 + 32 + row16) * BUu;
  const float bf1 = bff1[ig];
  const float bf2 = bff2[ig];
  const float btab = bta[ig] + btb[ig];
  float* L3 = (float*)(smem + 57344);

#pragma unroll 1
  for (int t = 0; t < Tt; ++t) {
    // ========== S1: z1 = lecun(cat(x_t,h) @ Wb1^T + bb1) ==========
    {
      const float* xrow = xbase + (size_t)t * Ii;
      f32x4 acc0 = {0.f, 0.f, 0.f, 0.f}, acc1 = {0.f, 0.f, 0.f, 0.f};
#pragma unroll
      for (int kc = 0; kc < 24; ++kc) {
        const int k0 = (kc << 5) + (kg << 3);
        bf16x8 a;
        if (kc < 8) {               // x part (fp32 -> bf16 on the fly)
          const float* xp = xrow + k0;
#pragma unroll
          for (int j = 0; j < 8; ++j) a[j] = f2bf(xp[j]);
        } else {                    // h part (bf16)
          a = *(const bf16x8*)(hrow + (k0 - 256));
        }
        const bf16x8 b = *(const bf16x8*)(smem + row16 * 1536 + (((kc << 6) + kg16) ^ swzm));
        if (kc & 1) acc1 = __builtin_amdgcn_mfma_f32_16x16x32_bf16(a, b, acc1, 0, 0, 0);
        else        acc0 = __builtin_amdgcn_mfma_f32_16x16x32_bf16(a, b, acc0, 0, 0, 0);
      }
#pragma unroll
      for (int i = 0; i < 4; ++i) {
        float v = acc0[i] + acc1[i] + bias1;   // D: row=(lane>>4)*4+i, col=lane&15
        z1[(b0 + rbase + i) * BUu + (n0 + row16)] = f2bf(lecun_act(v));
      }
    }
    gbar(flags, wg, lane, 3u * t + 1u);

    // ========== S2: z2 = lecun(z1 @ Wb2^T + bb2) ==========
    {
      f32x4 acc0 = {0.f, 0.f, 0.f, 0.f}, acc1 = {0.f, 0.f, 0.f, 0.f};
#pragma unroll
      for (int kc = 0; kc < 32; ++kc) {
        const bf16x8 a = *(const bf16x8*)(z1row + (kc << 5) + (kg << 3));
        const bf16x8 b = *(const bf16x8*)(smem + 24576 + row16 * 2048 + (((kc << 6) + kg16) ^ swzm));
        if (kc & 1) acc1 = __builtin_amdgcn_mfma_f32_16x16x32_bf16(a, b, acc1, 0, 0, 0);
        else        acc0 = __builtin_amdgcn_mfma_f32_16x16x32_bf16(a, b, acc0, 0, 0, 0);
      }
#pragma unroll
      for (int i = 0; i < 4; ++i) {
        float v = acc0[i] + acc1[i] + bias2;
        z2[(b0 + rbase + i) * BUu + (n0 + row16)] = f2bf(lecun_act(v));
      }
    }
    gbar(flags, wg, lane, 3u * t + 2u);

    // ========== S3: heads + gate + h_new + ys (wgs 0..127) ==========
    if (wg < 128) {
      f32x4 a00 = {0.f,0.f,0.f,0.f}, a01 = {0.f,0.f,0.f,0.f};
      f32x4 a10 = {0.f,0.f,0.f,0.f}, a11 = {0.f,0.f,0.f,0.f};
      f32x4 a20 = {0.f,0.f,0.f,0.f}, a21 = {0.f,0.f,0.f,0.f};
#pragma unroll
      for (int kc = 0; kc < 32; ++kc) {
        const int koff = (kc << 5) + (kg << 3);
        const bf16x8 a  = *(const bf16x8*)(z2row + koff);
        const bf16x8 w0 = *(const bf16x8*)(wh0 + koff);
        const bf16x8 w1 = *(const bf16x8*)(wh1 + koff);
        const bf16x8 w2 = *(const bf16x8*)(wh2 + koff);
        if (kc & 1) {
          a01 = __builtin_amdgcn_mfma_f32_16x16x32_bf16(a, w0, a01, 0, 0, 0);
          a11 = __builtin_amdgcn_mfma_f32_16x16x32_bf16(a, w1, a11, 0, 0, 0);
          a21 = __builtin_amdgcn_mfma_f32_16x16x32_bf16(a, w2, a21, 0, 0, 0);
        } else {
          a00 = __builtin_amdgcn_mfma_f32_16x16x32_bf16(a, w0, a00, 0, 0, 0);
          a10 = __builtin_amdgcn_mfma_f32_16x16x32_bf16(a, w1, a10, 0, 0, 0);
          a20 = __builtin_amdgcn_mfma_f32_16x16x32_bf16(a, w2, a20, 0, 0, 0);
        }
      }
      // stage raw dots to LDS: [16 rows][48 cols = 16 (i,head) triplets]
#pragma unroll
      for (int i = 0; i < 4; ++i) {
        L3[(rbase + i) * 48 + 0  + row16] = a00[i] + a01[i];
        L3[(rbase + i) * 48 + 16 + row16] = a10[i] + a11[i];
        L3[(rbase + i) * 48 + 32 + row16] = a20[i] + a21[i];
      }
      __syncthreads();
#pragma unroll
      for (int q = 0; q < 4; ++q) {
        const int mm = kg + (q << 2);  // batch row 0..15 within tile
        const float a0 = L3[mm * 48 + 3 * row16 + 0];
        const float a1 = L3[mm * 48 + 3 * row16 + 1];
        const float a2 = L3[mm * 48 + 3 * row16 + 2];
        const float ff1 = fast_tanh(a0 + bf1);
        const float ff2 = fast_tanh(a1 + bf2);
        const float tt = fast_sig(a2 + btab);
        const float hn = ff1 + tt * (ff2 - ff1);
        const int brow = b03 + mm;
        hb[brow * Hh + ig] = f2bf(hn);
        out[((size_t)brow * Tt + t) * Hh + ig] = hn;
      }
    }
    if (t < Tt - 1) gbar(flags, wg, lane, 3u * t + 3u);
  }
}

extern "C" void kernel_launch(void* const* d_in, const int* in_sizes, int n_in,
                              void* d_out, int out_size, void* d_ws, size_t ws_size,
                              hipStream_t stream) {
  const float* x    = (const float*)d_in[0];
  const float* wb1  = (const float*)d_in[1];
  const float* bb1  = (const float*)d_in[2];
  const float* wb2  = (const float*)d_in[3];
  const float* bb2  = (const float*)d_in[4];
  const float* wff1 = (const float*)d_in[5];
  const float* bff1 = (const float*)d_in[6];
  const float* wff2 = (const float*)d_in[7];
  const float* bff2 = (const float*)d_in[8];
  const float* wta  = (const float*)d_in[9];
  const float* bta  = (const float*)d_in[10];
  const float* wtb  = (const float*)d_in[11];
  const float* btb  = (const float*)d_in[12];
  unsigned char* ws = (unsigned char*)d_ws;

  const unsigned prep_items = 786432u + 1048576u + 1572864u + 32768u + 256u;
  cfc_prep<<<(prep_items + 255u) / 256u, 256, 0, stream>>>(wb1, wb2, wff1, wff2, wta, wtb, ws);
  cfc_run<<<256, 64, 0, stream>>>(x, bb1, bb2, bff1, bff2, bta, btb, ws, (float*)d_out);
}

// Round 2
// 14635.764 us; speedup vs baseline: 2.3225x; 2.3225x over previous
//
#include <hip/hip_runtime.h>
#include <hip/hip_bf16.h>

// CfC recurrent net. B=64,T=512,I=256,H=512,BU=1024.
// Persistent kernel: 256 wgs x 64 threads (1 wave), 1 wg/CU (LDS-forced).
// Cross-wg data via agent-scope RELAXED atomics (sc1: LLC-coherent, L2-bypass)
// -> zero acquire-invalidate fences, weights stay hot in LDS/L2.
// Barrier: padded per-wg flags + master aggregation + 8x-replicated epoch.

#define Tt  512
#define Ii  256
#define Hh  512
#define BUu 1024
#define KC  768   // I+H

typedef __attribute__((ext_vector_type(8))) short bf16x8;   // 8 bf16 = 4 VGPR
typedef __attribute__((ext_vector_type(4))) float f32x4;
typedef unsigned long long u64;

// ---- workspace layout (bytes) ----
#define OFF_WB1   0u         // bf16 [1024][768]
#define OFF_WB2   1572864u   // bf16 [1024][1024]
#define OFF_WHD   3670016u   // bf16 [1536][1024], row c = 3*i+head (head2 = wta+wtb)
#define OFF_Z1    6815744u   // bf16 [64][1024]
#define OFF_Z2    6946816u   // bf16 [64][1024]
#define OFF_H     7077888u   // bf16 [64][512]
#define OFF_FLAGS 7143424u   // uint [256] padded to 64B stride (16 KB)
#define OFF_EPOCH 7159808u   // uint [8] padded to 64B stride (512 B)

// ---- LDS layout (dynamic, 108096 B) ----
#define SM_WB1   0        // 16 rows x 1536 B (K=768)
#define SM_WB2   24576    // 16 rows x 2048 B (K=1024)
#define SM_WHD   57344    // 24 rows x 2048 B (K=1024)
#define SM_STAGE 106496   // 1600 B stage (S1/S2: 512B transpose; S3: 16x25 f32)
#define SM_TOTAL 108096

__device__ __forceinline__ short f2bf(float f) {   // fp32 -> bf16 RNE
  unsigned u = __builtin_bit_cast(unsigned, f);
  u += 0x7FFFu + ((u >> 16) & 1u);
  return (short)(u >> 16);
}
__device__ __forceinline__ float fast_tanh(float u) {
  float e = __expf(2.0f * u);
  return (e - 1.0f) / (e + 1.0f);
}
__device__ __forceinline__ float fast_sig(float x) {
  return 1.0f / (1.0f + __expf(-x));
}
__device__ __forceinline__ float lecun_act(float u) {
  return 1.7159f * fast_tanh(0.666f * u);
}

// LLC-coherent (agent-scope relaxed) data movement: bypasses L2 both ways.
__device__ __forceinline__ u64 ld8c(const void* p) {
  return __hip_atomic_load((const u64*)p, __ATOMIC_RELAXED, __HIP_MEMORY_SCOPE_AGENT);
}
__device__ __forceinline__ void st8c(void* p, u64 v) {
  __hip_atomic_store((u64*)p, v, __ATOMIC_RELAXED, __HIP_MEMORY_SCOPE_AGENT);
}
__device__ __forceinline__ bf16x8 ld16c(const void* p) {
  union { u64 q[2]; bf16x8 v; } u;
  u.q[0] = ld8c(p);
  u.q[1] = ld8c((const char*)p + 8);
  return u.v;
}

// Device barrier: arrive (lane0 RELEASE flag) -> master wg scans 256 padded
// flags, publishes epoch to 8 per-XCD-slot copies; others poll 1 coalesced word.
__device__ __forceinline__ void barrier_sync(unsigned* flags, unsigned* ep,
                                             int wg, int lane, unsigned g) {
  if (lane == 0)
    __hip_atomic_store(flags + (unsigned)wg * 16u, g, __ATOMIC_RELEASE,
                       __HIP_MEMORY_SCOPE_AGENT);
  if (wg == 255) {
    const unsigned* f0 = flags + (unsigned)lane * 16u;
    for (;;) {
      unsigned a = __hip_atomic_load(f0 +    0u, __ATOMIC_RELAXED, __HIP_MEMORY_SCOPE_AGENT);
      unsigned b = __hip_atomic_load(f0 + 1024u, __ATOMIC_RELAXED, __HIP_MEMORY_SCOPE_AGENT);
      unsigned c = __hip_atomic_load(f0 + 2048u, __ATOMIC_RELAXED, __HIP_MEMORY_SCOPE_AGENT);
      unsigned d = __hip_atomic_load(f0 + 3072u, __ATOMIC_RELAXED, __HIP_MEMORY_SCOPE_AGENT);
      if (__all((int)((a >= g) && (b >= g) && (c >= g) && (d >= g)))) break;
      __builtin_amdgcn_s_sleep(2);
    }
    if (lane < 8)
      __hip_atomic_store(ep + (unsigned)lane * 16u, g, __ATOMIC_RELEASE,
                         __HIP_MEMORY_SCOPE_AGENT);
  } else {
    const unsigned* myep = ep + (unsigned)(wg & 7) * 16u;
    for (;;) {
      unsigned e = __hip_atomic_load(myep, __ATOMIC_RELAXED, __HIP_MEMORY_SCOPE_AGENT);
      if (e >= g) break;
      __builtin_amdgcn_s_sleep(2);
    }
  }
  __asm__ __volatile__("" ::: "memory");  // compiler fence; HW issues in order
}

// ---- prep: weight conversion to bf16, fused head matrix, zero h/flags ----
__global__ void cfc_prep(const float* __restrict__ wb1, const float* __restrict__ wb2,
                         const float* __restrict__ wff1, const float* __restrict__ wff2,
                         const float* __restrict__ wta, const float* __restrict__ wtb,
                         unsigned char* __restrict__ ws) {
  const unsigned N1 = 1024u * 768u;
  const unsigned N2 = 1024u * 1024u;
  const unsigned N3 = 1536u * 1024u;
  const unsigned NH = 64u * 512u;
  const unsigned NF = 4096u + 128u;   // flags (16KB) + epoch (512B) dwords
  unsigned idx = blockIdx.x * blockDim.x + threadIdx.x;
  short* Wb1 = (short*)(ws + OFF_WB1);
  short* Wb2 = (short*)(ws + OFF_WB2);
  short* Whd = (short*)(ws + OFF_WHD);
  short* Hbuf = (short*)(ws + OFF_H);
  unsigned* flags = (unsigned*)(ws + OFF_FLAGS);
  if (idx < N1) { Wb1[idx] = f2bf(wb1[idx]); return; }
  idx -= N1;
  if (idx < N2) { Wb2[idx] = f2bf(wb2[idx]); return; }
  idx -= N2;
  if (idx < N3) {
    unsigned c = idx >> 10, k = idx & 1023u;
    unsigned i = c / 3u, hd = c % 3u;
    float v = (hd == 0u) ? wff1[i * 1024u + k]
            : (hd == 1u) ? wff2[i * 1024u + k]
                         : (wta[i * 1024u + k] + wtb[i * 1024u + k]);
    Whd[idx] = f2bf(v);
    return;
  }
  idx -= N3;
  if (idx < NH) { Hbuf[idx] = 0; return; }
  idx -= NH;
  if (idx < NF) { flags[idx] = 0u; }
}

// ---- persistent recurrent kernel ----
__global__ __launch_bounds__(64) void cfc_run(
    const float* __restrict__ x,
    const float* __restrict__ bb1, const float* __restrict__ bb2,
    const float* __restrict__ bff1, const float* __restrict__ bff2,
    const float* __restrict__ bta, const float* __restrict__ btb,
    unsigned char* __restrict__ ws, float* __restrict__ out) {
  extern __shared__ char smem[];
  const int wg = blockIdx.x;     // 0..255
  const int lane = threadIdx.x;  // 0..63
  const short* Wb1 = (const short*)(ws + OFF_WB1);
  const short* Wb2 = (const short*)(ws + OFF_WB2);
  const short* Whd = (const short*)(ws + OFF_WHD);
  short* z1 = (short*)(ws + OFF_Z1);
  short* z2 = (short*)(ws + OFF_Z2);
  short* hb = (short*)(ws + OFF_H);
  unsigned* flags = (unsigned*)(ws + OFF_FLAGS);
  unsigned* epoch = (unsigned*)(ws + OFF_EPOCH);

  // Job split (same for all stages): bt = wg>>6 (16 batch rows), sub = wg&63.
  // S1/S2: sub = n-tile (16 cols).  S3: sub = i-octet (8 outputs, 24 Whd rows).
  const int bt = wg >> 6, sub = wg & 63;
  const int b0 = bt << 4;
  const int n0 = sub << 4;          // S1/S2 output cols
  const int ib = sub << 3;          // S3 output i-base (8 i's)
  const int c0 = sub * 24;          // S3 Whd row base (3*ib)

  const int row16 = lane & 15;       // A-row / B-col index of this lane
  const int kg = lane >> 4;          // k-group 0..3 (8 bf16 each)
  const int kg16 = kg << 4;          // byte offset of k-group
  const int swzm = (row16 & 7) << 4; // LDS row xor-swizzle
  const int rbase = kg << 2;         // D rows = rbase..rbase+3

  // ---- one-time LDS preload (xor-swizzled rows) ----
  for (int c = lane; c < 16 * 96; c += 64) {
    int r = c / 96, kb = (c % 96) << 4;
    *(bf16x8*)(smem + SM_WB1 + r * 1536 + (kb ^ ((r & 7) << 4))) =
        *(const bf16x8*)(Wb1 + (size_t)(n0 + r) * KC + (kb >> 1));
  }
  for (int c = lane; c < 16 * 128; c += 64) {
    int r = c >> 7, kb = (c & 127) << 4;
    *(bf16x8*)(smem + SM_WB2 + r * 2048 + (kb ^ ((r & 7) << 4))) =
        *(const bf16x8*)(Wb2 + (size_t)(n0 + r) * BUu + (kb >> 1));
  }
  for (int c = lane; c < 24 * 128; c += 64) {
    int r = c >> 7, kb = (c & 127) << 4;
    *(bf16x8*)(smem + SM_WHD + r * 2048 + (kb ^ ((r & 7) << 4))) =
        *(const bf16x8*)(Whd + (size_t)(c0 + r) * BUu + (kb >> 1));
  }
  __syncthreads();

  // hoisted per-lane constants
  const float bias1 = bb1[n0 + row16];
  const float bias2 = bb2[n0 + row16];
  const short* hrow = hb + (b0 + row16) * Hh;
  const float* xbase = x + (size_t)(b0 + row16) * Tt * Ii;
  const short* z1row = z1 + (b0 + row16) * BUu;
  const short* z2row = z2 + (b0 + row16) * BUu;
  // S3 epilogue mapping: lane -> (batch row r3, i-pair iq)
  const int r3 = lane >> 2, iq = lane & 3;
  float bF1[2], bF2[2], bTT[2];
#pragma unroll
  for (int jj = 0; jj < 2; ++jj) {
    const int ig = ib + (iq << 1) + jj;
    bF1[jj] = bff1[ig];
    bF2[jj] = bff2[ig];
    bTT[jj] = bta[ig] + btb[ig];
  }
  short* T = (short*)(smem + SM_STAGE);   // 16x16 bf16 transpose tile
  float* L3 = (float*)(smem + SM_STAGE);  // 16x25 f32 S3 stage

#pragma unroll 1
  for (int t = 0; t < Tt; ++t) {
    // ========== S1: z1 = lecun(cat(x_t,h) @ Wb1^T + bb1) ==========
    {
      const float* xrow = xbase + (size_t)t * Ii;
      f32x4 acc0 = {0.f, 0.f, 0.f, 0.f}, acc1 = {0.f, 0.f, 0.f, 0.f};
#pragma unroll
      for (int kc = 0; kc < 24; ++kc) {
        bf16x8 a;
        if (kc < 8) {               // x part (fp32 -> bf16 on the fly)
          const float* xp = xrow + (kc << 5) + (kg << 3);
          const f32x4 xa = *(const f32x4*)xp;
          const f32x4 xb = *(const f32x4*)(xp + 4);
#pragma unroll
          for (int j = 0; j < 4; ++j) { a[j] = f2bf(xa[j]); a[4 + j] = f2bf(xb[j]); }
        } else {                    // h part (LLC-coherent)
          a = ld16c(hrow + ((kc - 8) << 5) + (kg << 3));
        }
        const bf16x8 b = *(const bf16x8*)(smem + SM_WB1 + row16 * 1536 + (((kc << 6) + kg16) ^ swzm));
        if (kc & 1) acc1 = __builtin_amdgcn_mfma_f32_16x16x32_bf16(a, b, acc1, 0, 0, 0);
        else        acc0 = __builtin_amdgcn_mfma_f32_16x16x32_bf16(a, b, acc0, 0, 0, 0);
      }
#pragma unroll
      for (int i = 0; i < 4; ++i)
        T[(rbase + i) * 16 + row16] = f2bf(lecun_act(acc0[i] + acc1[i] + bias1));
      __syncthreads();
      const int rr = lane >> 2, cc = (lane & 3) << 2;
      const u64 v = *(const u64*)(T + rr * 16 + cc);
      st8c(z1 + (size_t)(b0 + rr) * BUu + n0 + cc, v);
    }
    barrier_sync(flags, epoch, wg, lane, 3u * t + 1u);

    // ========== S2: z2 = lecun(z1 @ Wb2^T + bb2) ==========
    {
      f32x4 acc0 = {0.f, 0.f, 0.f, 0.f}, acc1 = {0.f, 0.f, 0.f, 0.f};
#pragma unroll
      for (int kc = 0; kc < 32; ++kc) {
        const bf16x8 a = ld16c(z1row + (kc << 5) + (kg << 3));
        const bf16x8 b = *(const bf16x8*)(smem + SM_WB2 + row16 * 2048 + (((kc << 6) + kg16) ^ swzm));
        if (kc & 1) acc1 = __builtin_amdgcn_mfma_f32_16x16x32_bf16(a, b, acc1, 0, 0, 0);
        else        acc0 = __builtin_amdgcn_mfma_f32_16x16x32_bf16(a, b, acc0, 0, 0, 0);
      }
      __syncthreads();   // protect T reuse across stages
#pragma unroll
      for (int i = 0; i < 4; ++i)
        T[(rbase + i) * 16 + row16] = f2bf(lecun_act(acc0[i] + acc1[i] + bias2));
      __syncthreads();
      const int rr = lane >> 2, cc = (lane & 3) << 2;
      const u64 v = *(const u64*)(T + rr * 16 + cc);
      st8c(z2 + (size_t)(b0 + rr) * BUu + n0 + cc, v);
    }
    barrier_sync(flags, epoch, wg, lane, 3u * t + 2u);

    // ========== S3: heads + gate + h_new + ys (all 256 wgs) ==========
    {
      f32x4 p00 = {0.f,0.f,0.f,0.f}, p01 = {0.f,0.f,0.f,0.f};
      f32x4 p10 = {0.f,0.f,0.f,0.f}, p11 = {0.f,0.f,0.f,0.f};
#pragma unroll
      for (int kc = 0; kc < 32; ++kc) {
        const bf16x8 a = ld16c(z2row + (kc << 5) + (kg << 3));
        const int kb = ((kc << 6) + kg16) ^ swzm;
        const bf16x8 w0 = *(const bf16x8*)(smem + SM_WHD + row16 * 2048 + kb);
        const bf16x8 w1 = *(const bf16x8*)(smem + SM_WHD + (16 + (row16 & 7)) * 2048 + kb);
        if (kc & 1) {
          p01 = __builtin_amdgcn_mfma_f32_16x16x32_bf16(a, w0, p01, 0, 0, 0);
          p11 = __builtin_amdgcn_mfma_f32_16x16x32_bf16(a, w1, p11, 0, 0, 0);
        } else {
          p00 = __builtin_amdgcn_mfma_f32_16x16x32_bf16(a, w0, p00, 0, 0, 0);
          p10 = __builtin_amdgcn_mfma_f32_16x16x32_bf16(a, w1, p10, 0, 0, 0);
        }
      }
      __syncthreads();   // protect stage reuse
      // stage raw dots: L3[16 rows][24 cols(+pad)]; col lc = 3*i_local + head
#pragma unroll
      for (int i = 0; i < 4; ++i) {
        L3[(rbase + i) * 25 + row16] = p00[i] + p01[i];
        if (row16 < 8) L3[(rbase + i) * 25 + 16 + row16] = p10[i] + p11[i];
      }
      __syncthreads();
      unsigned hv = 0;
      float outv[2];
#pragma unroll
      for (int jj = 0; jj < 2; ++jj) {
        const int il = (iq << 1) + jj;     // local i 0..7
        const float a0 = L3[r3 * 25 + 3 * il + 0];
        const float a1 = L3[r3 * 25 + 3 * il + 1];
        const float a2 = L3[r3 * 25 + 3 * il + 2];
        const float ff1 = fast_tanh(a0 + bF1[jj]);
        const float ff2 = fast_tanh(a1 + bF2[jj]);
        const float tt  = fast_sig(a2 + bTT[jj]);
        const float hn = ff1 + tt * (ff2 - ff1);
        outv[jj] = hn;
        hv |= ((unsigned)(unsigned short)f2bf(hn)) << (16 * jj);
      }
      __hip_atomic_store((unsigned*)hb + (((b0 + r3) * Hh + ib + (iq << 1)) >> 1),
                         hv, __ATOMIC_RELAXED, __HIP_MEMORY_SCOPE_AGENT);
      float2 ov = { outv[0], outv[1] };
      *(float2*)(out + ((size_t)(b0 + r3) * Tt + t) * Hh + ib + (iq << 1)) = ov;
    }
    if (t < Tt - 1) barrier_sync(flags, epoch, wg, lane, 3u * t + 3u);
  }
}

extern "C" void kernel_launch(void* const* d_in, const int* in_sizes, int n_in,
                              void* d_out, int out_size, void* d_ws, size_t ws_size,
                              hipStream_t stream) {
  const float* x    = (const float*)d_in[0];
  const float* wb1  = (const float*)d_in[1];
  const float* bb1  = (const float*)d_in[2];
  const float* wb2  = (const float*)d_in[3];
  const float* bb2  = (const float*)d_in[4];
  const float* wff1 = (const float*)d_in[5];
  const float* bff1 = (const float*)d_in[6];
  const float* wff2 = (const float*)d_in[7];
  const float* bff2 = (const float*)d_in[8];
  const float* wta  = (const float*)d_in[9];
  const float* bta  = (const float*)d_in[10];
  const float* wtb  = (const float*)d_in[11];
  const float* btb  = (const float*)d_in[12];
  unsigned char* ws = (unsigned char*)d_ws;

  const unsigned prep_items = 786432u + 1048576u + 1572864u + 32768u + 4224u;
  cfc_prep<<<(prep_items + 255u) / 256u, 256, 0, stream>>>(wb1, wb2, wff1, wff2, wta, wtb, ws);
  cfc_run<<<256, 64, SM_TOTAL, stream>>>(x, bb1, bb2, bff1, bff2, bta, btb, ws, (float*)d_out);
}

// Round 3
// 14226.389 us; speedup vs baseline: 2.3893x; 1.0288x over previous
//
#include <hip/hip_runtime.h>
#include <hip/hip_bf16.h>

// CfC recurrent net. B=64,T=512,I=256,H=512,BU=1024.
// Persistent kernel: 64 wgs x 256 threads (4 waves; wave=batch-tile).
// Cross-wg data via agent-scope RELAXED atomics (sc0+sc1: LLC-coherent).
// NO release/acquire anywhere -> no buffer_wbl2/inv; __syncthreads provides
// the vmcnt(0) drain before the relaxed flag store.
// Barrier: one-hop, 64 padded flags, every wave polls all 64 (__all).
// S1's x-part (K=256) is computed between arrive and wait of barrier 3
// (input-only dependency) -> off the critical path.

#define Tt  512
#define Ii  256
#define Hh  512
#define BUu 1024
#define KC  768   // I+H
#define NWG 64

typedef __attribute__((ext_vector_type(8))) short bf16x8;   // 8 bf16 = 4 VGPR
typedef __attribute__((ext_vector_type(4))) float f32x4;
typedef unsigned long long u64;

// ---- workspace layout (bytes) ----
#define OFF_WB1   0u         // bf16 [1024][768]
#define OFF_WB2   1572864u   // bf16 [1024][1024]
#define OFF_WHD   3670016u   // bf16 [1536][1024], row c = 3*i+head (head2 = wta+wtb)
#define OFF_Z1    6815744u   // bf16 [64][1024]
#define OFF_Z2    6946816u   // bf16 [64][1024]
#define OFF_H     7077888u   // bf16 [64][512]
#define OFF_FLAGS 7143424u   // uint [64] padded to 64B stride (4 KB)

// ---- LDS layout (dynamic) ----
#define SM_WB1   0        // 16 rows x 1536 B (K=768)
#define SM_WB2   24576    // 16 rows x 2048 B (K=1024)
#define SM_WHD   57344    // 24 rows x 2048 B (K=1024)
#define SM_STAGE 106496   // per-wave 1600 B stage (transpose / S3 dots)
#define SM_TOTAL (106496 + 4 * 1600)

__device__ __forceinline__ short f2bf(float f) {   // fp32 -> bf16 RNE
  unsigned u = __builtin_bit_cast(unsigned, f);
  u += 0x7FFFu + ((u >> 16) & 1u);
  return (short)(u >> 16);
}
__device__ __forceinline__ float fast_tanh(float u) {
  float e = __expf(2.0f * u);
  return (e - 1.0f) / (e + 1.0f);
}
__device__ __forceinline__ float fast_sig(float x) {
  return 1.0f / (1.0f + __expf(-x));
}
__device__ __forceinline__ float lecun_act(float u) {
  return 1.7159f * fast_tanh(0.666f * u);
}

// LLC-coherent (agent-scope relaxed) data movement: bypasses L1/L2 both ways.
__device__ __forceinline__ u64 ld8c(const void* p) {
  return __hip_atomic_load((const u64*)p, __ATOMIC_RELAXED, __HIP_MEMORY_SCOPE_AGENT);
}
__device__ __forceinline__ void st8c(void* p, u64 v) {
  __hip_atomic_store((u64*)p, v, __ATOMIC_RELAXED, __HIP_MEMORY_SCOPE_AGENT);
}
__device__ __forceinline__ bf16x8 ld16c(const void* p) {
  union { u64 q[2]; bf16x8 v; } u;
  u.q[0] = ld8c(p);
  u.q[1] = ld8c((const char*)p + 8);
  return u.v;
}

// arrive: syncthreads drains vmcnt(0) for ALL waves' sc1 stores, then one
// RELAXED flag store (no wbl2).  wait: every wave polls all 64 flags.
__device__ __forceinline__ void bar_arrive(unsigned* flags, int wg, int tid, unsigned g) {
  __syncthreads();
  if (tid == 0)
    __hip_atomic_store(flags + (unsigned)wg * 16u, g, __ATOMIC_RELAXED,
                       __HIP_MEMORY_SCOPE_AGENT);
}
__device__ __forceinline__ void bar_wait(const unsigned* flags, int lane, unsigned g) {
  const unsigned* fp = flags + (unsigned)lane * 16u;  // lane L watches wg L
  for (;;) {
    unsigned f = __hip_atomic_load(fp, __ATOMIC_RELAXED, __HIP_MEMORY_SCOPE_AGENT);
    if (__all((int)(f >= g))) break;
    __builtin_amdgcn_s_sleep(1);
  }
  __asm__ __volatile__("" ::: "memory");
}

// ---- prep: weight conversion to bf16, fused head matrix, zero h/flags ----
__global__ void cfc_prep(const float* __restrict__ wb1, const float* __restrict__ wb2,
                         const float* __restrict__ wff1, const float* __restrict__ wff2,
                         const float* __restrict__ wta, const float* __restrict__ wtb,
                         unsigned char* __restrict__ ws) {
  const unsigned N1 = 1024u * 768u;
  const unsigned N2 = 1024u * 1024u;
  const unsigned N3 = 1536u * 1024u;
  const unsigned NH = 64u * 512u;
  const unsigned NF = 1024u;   // flag region dwords
  unsigned idx = blockIdx.x * blockDim.x + threadIdx.x;
  short* Wb1 = (short*)(ws + OFF_WB1);
  short* Wb2 = (short*)(ws + OFF_WB2);
  short* Whd = (short*)(ws + OFF_WHD);
  short* Hbuf = (short*)(ws + OFF_H);
  unsigned* flags = (unsigned*)(ws + OFF_FLAGS);
  if (idx < N1) { Wb1[idx] = f2bf(wb1[idx]); return; }
  idx -= N1;
  if (idx < N2) { Wb2[idx] = f2bf(wb2[idx]); return; }
  idx -= N2;
  if (idx < N3) {
    unsigned c = idx >> 10, k = idx & 1023u;
    unsigned i = c / 3u, hd = c % 3u;
    float v = (hd == 0u) ? wff1[i * 1024u + k]
            : (hd == 1u) ? wff2[i * 1024u + k]
                         : (wta[i * 1024u + k] + wtb[i * 1024u + k]);
    Whd[idx] = f2bf(v);
    return;
  }
  idx -= N3;
  if (idx < NH) { Hbuf[idx] = 0; return; }
  idx -= NH;
  if (idx < NF) { flags[idx] = 0u; }
}

// ---- persistent recurrent kernel ----
__global__ __launch_bounds__(256) void cfc_run(
    const float* __restrict__ x,
    const float* __restrict__ bb1, const float* __restrict__ bb2,
    const float* __restrict__ bff1, const float* __restrict__ bff2,
    const float* __restrict__ bta, const float* __restrict__ btb,
    unsigned char* __restrict__ ws, float* __restrict__ out) {
  extern __shared__ char smem[];
  const int wg = blockIdx.x;           // 0..63  (column-slice / i-octet)
  const int tid = threadIdx.x;         // 0..255
  const int wave = tid >> 6;           // 0..3   (batch tile)
  const int lane = tid & 63;
  const short* Wb1 = (const short*)(ws + OFF_WB1);
  const short* Wb2 = (const short*)(ws + OFF_WB2);
  const short* Whd = (const short*)(ws + OFF_WHD);
  short* z1 = (short*)(ws + OFF_Z1);
  short* z2 = (short*)(ws + OFF_Z2);
  short* hb = (short*)(ws + OFF_H);
  unsigned* flags = (unsigned*)(ws + OFF_FLAGS);

  const int b0 = wave << 4;            // 16 batch rows per wave
  const int n0 = wg << 4;              // S1/S2 output cols
  const int ib = wg << 3;              // S3 output i-base (8 i's)
  const int c0 = wg * 24;              // S3 Whd row base

  const int row16 = lane & 15;         // A-row / B-col index of this lane
  const int kg = lane >> 4;            // k-group 0..3 (8 bf16 each)
  const int kg16 = kg << 4;            // byte offset of k-group
  const int swzm = (row16 & 7) << 4;   // LDS row xor-swizzle
  const int rbase = kg << 2;           // D rows = rbase..rbase+3

  // ---- one-time LDS preload (xor-swizzled rows; shared by the 4 waves) ----
  for (int c = tid; c < 16 * 96; c += 256) {
    int r = c / 96, kb = (c % 96) << 4;
    *(bf16x8*)(smem + SM_WB1 + r * 1536 + (kb ^ ((r & 7) << 4))) =
        *(const bf16x8*)(Wb1 + (size_t)(n0 + r) * KC + (kb >> 1));
  }
  for (int c = tid; c < 16 * 128; c += 256) {
    int r = c >> 7, kb = (c & 127) << 4;
    *(bf16x8*)(smem + SM_WB2 + r * 2048 + (kb ^ ((r & 7) << 4))) =
        *(const bf16x8*)(Wb2 + (size_t)(n0 + r) * BUu + (kb >> 1));
  }
  for (int c = tid; c < 24 * 128; c += 256) {
    int r = c >> 7, kb = (c & 127) << 4;
    *(bf16x8*)(smem + SM_WHD + r * 2048 + (kb ^ ((r & 7) << 4))) =
        *(const bf16x8*)(Whd + (size_t)(c0 + r) * BUu + (kb >> 1));
  }
  __syncthreads();

  // hoisted per-lane constants
  const float bias1 = bb1[n0 + row16];
  const float bias2 = bb2[n0 + row16];
  const short* hrow = hb + (b0 + row16) * Hh;
  const float* xbase = x + (size_t)(b0 + row16) * Tt * Ii;
  const short* z1row = z1 + (b0 + row16) * BUu;
  const short* z2row = z2 + (b0 + row16) * BUu;
  const int r3 = lane >> 2, iq = lane & 3;   // S3 epilogue mapping
  float bF1[2], bF2[2], bTT[2];
#pragma unroll
  for (int jj = 0; jj < 2; ++jj) {
    const int ig = ib + (iq << 1) + jj;
    bF1[jj] = bff1[ig];
    bF2[jj] = bff2[ig];
    bTT[jj] = bta[ig] + btb[ig];
  }
  short* T = (short*)(smem + SM_STAGE + wave * 1600);   // 16x16 bf16 transpose
  float* L3 = (float*)(smem + SM_STAGE + wave * 1600);  // 16x25 f32 S3 stage

  // x-part of S1 (kc 0..7, input-only): computed off the critical path.
  f32x4 xa0, xa1;
  auto xpart = [&](int t, f32x4& a0, f32x4& a1) {
    const float* xrow = xbase + (size_t)t * Ii;
    a0 = f32x4{0.f, 0.f, 0.f, 0.f};
    a1 = f32x4{0.f, 0.f, 0.f, 0.f};
#pragma unroll
    for (int kc = 0; kc < 8; ++kc) {
      const float* xp = xrow + (kc << 5) + (kg << 3);
      const f32x4 va = *(const f32x4*)xp;
      const f32x4 vb = *(const f32x4*)(xp + 4);
      bf16x8 a;
#pragma unroll
      for (int j = 0; j < 4; ++j) { a[j] = f2bf(va[j]); a[4 + j] = f2bf(vb[j]); }
      const bf16x8 b = *(const bf16x8*)(smem + SM_WB1 + row16 * 1536 + (((kc << 6) + kg16) ^ swzm));
      if (kc & 1) a1 = __builtin_amdgcn_mfma_f32_16x16x32_bf16(a, b, a1, 0, 0, 0);
      else        a0 = __builtin_amdgcn_mfma_f32_16x16x32_bf16(a, b, a0, 0, 0, 0);
    }
  };
  xpart(0, xa0, xa1);

#pragma unroll 1
  for (int t = 0; t < Tt; ++t) {
    if (t) bar_wait(flags, lane, 3u * t);   // h(t-1) visible at LLC

    // ========== S1: z1 = lecun(cat(x_t,h) @ Wb1^T + bb1), h-part K=512 ==========
    {
      f32x4 acc0 = xa0, acc1 = xa1;
#pragma unroll
      for (int kc = 8; kc < 24; ++kc) {
        const bf16x8 a = ld16c(hrow + ((kc - 8) << 5) + (kg << 3));
        const bf16x8 b = *(const bf16x8*)(smem + SM_WB1 + row16 * 1536 + (((kc << 6) + kg16) ^ swzm));
        if (kc & 1) acc1 = __builtin_amdgcn_mfma_f32_16x16x32_bf16(a, b, acc1, 0, 0, 0);
        else        acc0 = __builtin_amdgcn_mfma_f32_16x16x32_bf16(a, b, acc0, 0, 0, 0);
      }
#pragma unroll
      for (int i = 0; i < 4; ++i)
        T[(rbase + i) * 16 + row16] = f2bf(lecun_act(acc0[i] + acc1[i] + bias1));
      __syncthreads();
      const int rr = lane >> 2, cc = (lane & 3) << 2;
      const u64 v = *(const u64*)(T + rr * 16 + cc);
      st8c(z1 + (size_t)(b0 + rr) * BUu + n0 + cc, v);
    }
    bar_arrive(flags, wg, tid, 3u * t + 1u);
    bar_wait(flags, lane, 3u * t + 1u);

    // ========== S2: z2 = lecun(z1 @ Wb2^T + bb2) ==========
    {
      f32x4 acc0 = {0.f, 0.f, 0.f, 0.f}, acc1 = {0.f, 0.f, 0.f, 0.f};
#pragma unroll
      for (int kc = 0; kc < 32; ++kc) {
        const bf16x8 a = ld16c(z1row + (kc << 5) + (kg << 3));
        const bf16x8 b = *(const bf16x8*)(smem + SM_WB2 + row16 * 2048 + (((kc << 6) + kg16) ^ swzm));
        if (kc & 1) acc1 = __builtin_amdgcn_mfma_f32_16x16x32_bf16(a, b, acc1, 0, 0, 0);
        else        acc0 = __builtin_amdgcn_mfma_f32_16x16x32_bf16(a, b, acc0, 0, 0, 0);
      }
      __syncthreads();   // WAR: T was read at end of S1
#pragma unroll
      for (int i = 0; i < 4; ++i)
        T[(rbase + i) * 16 + row16] = f2bf(lecun_act(acc0[i] + acc1[i] + bias2));
      __syncthreads();
      const int rr = lane >> 2, cc = (lane & 3) << 2;
      const u64 v = *(const u64*)(T + rr * 16 + cc);
      st8c(z2 + (size_t)(b0 + rr) * BUu + n0 + cc, v);
    }
    bar_arrive(flags, wg, tid, 3u * t + 2u);
    bar_wait(flags, lane, 3u * t + 2u);

    // ========== S3: heads + gate + h_new + ys ==========
    {
      f32x4 p00 = {0.f,0.f,0.f,0.f}, p01 = {0.f,0.f,0.f,0.f};
      f32x4 p10 = {0.f,0.f,0.f,0.f}, p11 = {0.f,0.f,0.f,0.f};
#pragma unroll
      for (int kc = 0; kc < 32; ++kc) {
        const bf16x8 a = ld16c(z2row + (kc << 5) + (kg << 3));
        const int kb = ((kc << 6) + kg16) ^ swzm;
        const bf16x8 w0 = *(const bf16x8*)(smem + SM_WHD + row16 * 2048 + kb);
        const bf16x8 w1 = *(const bf16x8*)(smem + SM_WHD + (16 + (row16 & 7)) * 2048 + kb);
        if (kc & 1) {
          p01 = __builtin_amdgcn_mfma_f32_16x16x32_bf16(a, w0, p01, 0, 0, 0);
          p11 = __builtin_amdgcn_mfma_f32_16x16x32_bf16(a, w1, p11, 0, 0, 0);
        } else {
          p00 = __builtin_amdgcn_mfma_f32_16x16x32_bf16(a, w0, p00, 0, 0, 0);
          p10 = __builtin_amdgcn_mfma_f32_16x16x32_bf16(a, w1, p10, 0, 0, 0);
        }
      }
      __syncthreads();   // WAR: T was read at end of S2
      // stage raw dots: L3[16 rows][24 cols(+pad)]; col lc = 3*i_local + head
#pragma unroll
      for (int i = 0; i < 4; ++i) {
        L3[(rbase + i) * 25 + row16] = p00[i] + p01[i];
        if (row16 < 8) L3[(rbase + i) * 25 + 16 + row16] = p10[i] + p11[i];
      }
      __syncthreads();
      unsigned hv = 0;
      float outv[2];
#pragma unroll
      for (int jj = 0; jj < 2; ++jj) {
        const int il = (iq << 1) + jj;     // local i 0..7
        const float a0 = L3[r3 * 25 + 3 * il + 0];
        const float a1 = L3[r3 * 25 + 3 * il + 1];
        const float a2 = L3[r3 * 25 + 3 * il + 2];
        const float ff1 = fast_tanh(a0 + bF1[jj]);
        const float ff2 = fast_tanh(a1 + bF2[jj]);
        const float tt  = fast_sig(a2 + bTT[jj]);
        const float hn = ff1 + tt * (ff2 - ff1);
        outv[jj] = hn;
        hv |= ((unsigned)(unsigned short)f2bf(hn)) << (16 * jj);
      }
      __hip_atomic_store((unsigned*)hb + (((b0 + r3) * Hh + ib + (iq << 1)) >> 1),
                         hv, __ATOMIC_RELAXED, __HIP_MEMORY_SCOPE_AGENT);
      float2 ov = { outv[0], outv[1] };
      *(float2*)(out + ((size_t)(b0 + r3) * Tt + t) * Hh + ib + (iq << 1)) = ov;
    }
    bar_arrive(flags, wg, tid, 3u * t + 3u);
    if (t + 1 < Tt) xpart(t + 1, xa0, xa1);   // hidden under straggler wait
  }
}

extern "C" void kernel_launch(void* const* d_in, const int* in_sizes, int n_in,
                              void* d_out, int out_size, void* d_ws, size_t ws_size,
                              hipStream_t stream) {
  const float* x    = (const float*)d_in[0];
  const float* wb1  = (const float*)d_in[1];
  const float* bb1  = (const float*)d_in[2];
  const float* wb2  = (const float*)d_in[3];
  const float* bb2  = (const float*)d_in[4];
  const float* wff1 = (const float*)d_in[5];
  const float* bff1 = (const float*)d_in[6];
  const float* wff2 = (const float*)d_in[7];
  const float* bff2 = (const float*)d_in[8];
  const float* wta  = (const float*)d_in[9];
  const float* bta  = (const float*)d_in[10];
  const float* wtb  = (const float*)d_in[11];
  const float* btb  = (const float*)d_in[12];
  unsigned char* ws = (unsigned char*)d_ws;

  const unsigned prep_items = 786432u + 1048576u + 1572864u + 32768u + 1024u;
  cfc_prep<<<(prep_items + 255u) / 256u, 256, 0, stream>>>(wb1, wb2, wff1, wff2, wta, wtb, ws);
  cfc_run<<<NWG, 256, SM_TOTAL, stream>>>(x, bb1, bb2, bff1, bff2, bta, btb, ws, (float*)d_out);
}

// Round 4
// 13510.710 us; speedup vs baseline: 2.5159x; 1.0530x over previous
//
#include <hip/hip_runtime.h>
#include <hip/hip_bf16.h>

// CfC recurrent net. B=64,T=512,I=256,H=512,BU=1024.
// Persistent kernel: 64 wgs x 256 threads (4 waves; wave=batch-tile).
// Cross-wg data via agent-scope RELAXED atomics (LLC-coherent), no
// release/acquire anywhere (no wbl2/inv); __syncthreads drains vmcnt before
// the relaxed flag store.
// R4: burst register preloads per stage (all ~64 loads in flight -> ~1 RTT),
// dense 256B flag block (16x fewer poll transactions), s_sleep(2) backoff.

#define Tt  512
#define Ii  256
#define Hh  512
#define BUu 1024
#define KC  768   // I+H
#define NWG 64

typedef __attribute__((ext_vector_type(8))) short bf16x8;   // 8 bf16 = 4 VGPR
typedef __attribute__((ext_vector_type(4))) float f32x4;
typedef unsigned long long u64;

// ---- workspace layout (bytes) ----
#define OFF_WB1   0u         // bf16 [1024][768]
#define OFF_WB2   1572864u   // bf16 [1024][1024]
#define OFF_WHD   3670016u   // bf16 [1536][1024], row c = 3*i+head (head2 = wta+wtb)
#define OFF_Z1    6815744u   // bf16 [64][1024]
#define OFF_Z2    6946816u   // bf16 [64][1024]
#define OFF_H     7077888u   // bf16 [64][512]
#define OFF_FLAGS 7143424u   // uint [64] DENSE (256 B); region reserved 4 KB

// ---- LDS layout (dynamic) ----
#define SM_WB1   0        // 16 rows x 1536 B (K=768)
#define SM_WB2   24576    // 16 rows x 2048 B (K=1024)
#define SM_WHD   57344    // 24 rows x 2048 B (K=1024)
#define SM_STAGE 106496   // per-wave 1600 B stage (transpose / S3 dots)
#define SM_TOTAL (106496 + 4 * 1600)

__device__ __forceinline__ short f2bf(float f) {   // fp32 -> bf16 RNE
  unsigned u = __builtin_bit_cast(unsigned, f);
  u += 0x7FFFu + ((u >> 16) & 1u);
  return (short)(u >> 16);
}
__device__ __forceinline__ float fast_tanh(float u) {
  float e = __expf(2.0f * u);
  return (e - 1.0f) / (e + 1.0f);
}
__device__ __forceinline__ float fast_sig(float x) {
  return 1.0f / (1.0f + __expf(-x));
}
__device__ __forceinline__ float lecun_act(float u) {
  return 1.7159f * fast_tanh(0.666f * u);
}

// LLC-coherent (agent-scope relaxed) data movement.
__device__ __forceinline__ u64 ld8c(const void* p) {
  return __hip_atomic_load((const u64*)p, __ATOMIC_RELAXED, __HIP_MEMORY_SCOPE_AGENT);
}
__device__ __forceinline__ void st8c(void* p, u64 v) {
  __hip_atomic_store((u64*)p, v, __ATOMIC_RELAXED, __HIP_MEMORY_SCOPE_AGENT);
}
__device__ __forceinline__ bf16x8 ld16c(const void* p) {
  union { u64 q[2]; bf16x8 v; } u;
  u.q[0] = ld8c(p);
  u.q[1] = ld8c((const char*)p + 8);
  return u.v;
}

// arrive: syncthreads drains vmcnt(0) for ALL waves' sc1 stores, then one
// RELAXED flag store.  wait: every wave polls all 64 dense flags (256B).
__device__ __forceinline__ void bar_arrive(unsigned* flags, int wg, int tid, unsigned g) {
  __syncthreads();
  if (tid == 0)
    __hip_atomic_store(flags + (unsigned)wg, g, __ATOMIC_RELAXED,
                       __HIP_MEMORY_SCOPE_AGENT);
}
__device__ __forceinline__ void bar_wait(const unsigned* flags, int lane, unsigned g) {
  const unsigned* fp = flags + (unsigned)lane;  // lane L watches wg L
  for (;;) {
    unsigned f = __hip_atomic_load(fp, __ATOMIC_RELAXED, __HIP_MEMORY_SCOPE_AGENT);
    if (__all((int)(f >= g))) break;
    __builtin_amdgcn_s_sleep(2);
  }
  __asm__ __volatile__("" ::: "memory");
}

// ---- prep: weight conversion to bf16, fused head matrix, zero h/flags ----
__global__ void cfc_prep(const float* __restrict__ wb1, const float* __restrict__ wb2,
                         const float* __restrict__ wff1, const float* __restrict__ wff2,
                         const float* __restrict__ wta, const float* __restrict__ wtb,
                         unsigned char* __restrict__ ws) {
  const unsigned N1 = 1024u * 768u;
  const unsigned N2 = 1024u * 1024u;
  const unsigned N3 = 1536u * 1024u;
  const unsigned NH = 64u * 512u;
  const unsigned NF = 1024u;   // flag region dwords
  unsigned idx = blockIdx.x * blockDim.x + threadIdx.x;
  short* Wb1 = (short*)(ws + OFF_WB1);
  short* Wb2 = (short*)(ws + OFF_WB2);
  short* Whd = (short*)(ws + OFF_WHD);
  short* Hbuf = (short*)(ws + OFF_H);
  unsigned* flags = (unsigned*)(ws + OFF_FLAGS);
  if (idx < N1) { Wb1[idx] = f2bf(wb1[idx]); return; }
  idx -= N1;
  if (idx < N2) { Wb2[idx] = f2bf(wb2[idx]); return; }
  idx -= N2;
  if (idx < N3) {
    unsigned c = idx >> 10, k = idx & 1023u;
    unsigned i = c / 3u, hd = c % 3u;
    float v = (hd == 0u) ? wff1[i * 1024u + k]
            : (hd == 1u) ? wff2[i * 1024u + k]
                         : (wta[i * 1024u + k] + wtb[i * 1024u + k]);
    Whd[idx] = f2bf(v);
    return;
  }
  idx -= N3;
  if (idx < NH) { Hbuf[idx] = 0; return; }
  idx -= NH;
  if (idx < NF) { flags[idx] = 0u; }
}

// ---- persistent recurrent kernel ----
__global__ __launch_bounds__(256, 1) void cfc_run(
    const float* __restrict__ x,
    const float* __restrict__ bb1, const float* __restrict__ bb2,
    const float* __restrict__ bff1, const float* __restrict__ bff2,
    const float* __restrict__ bta, const float* __restrict__ btb,
    unsigned char* __restrict__ ws, float* __restrict__ out) {
  extern __shared__ char smem[];
  const int wg = blockIdx.x;           // 0..63  (column-slice / i-octet)
  const int tid = threadIdx.x;         // 0..255
  const int wave = tid >> 6;           // 0..3   (batch tile)
  const int lane = tid & 63;
  const short* Wb1 = (const short*)(ws + OFF_WB1);
  const short* Wb2 = (const short*)(ws + OFF_WB2);
  const short* Whd = (const short*)(ws + OFF_WHD);
  short* z1 = (short*)(ws + OFF_Z1);
  short* z2 = (short*)(ws + OFF_Z2);
  short* hb = (short*)(ws + OFF_H);
  unsigned* flags = (unsigned*)(ws + OFF_FLAGS);

  const int b0 = wave << 4;            // 16 batch rows per wave
  const int n0 = wg << 4;              // S1/S2 output cols
  const int ib = wg << 3;              // S3 output i-base (8 i's)
  const int c0 = wg * 24;              // S3 Whd row base

  const int row16 = lane & 15;         // A-row / B-col index of this lane
  const int kg = lane >> 4;            // k-group 0..3 (8 bf16 each)
  const int kg16 = kg << 4;            // byte offset of k-group
  const int swzm = (row16 & 7) << 4;   // LDS row xor-swizzle
  const int rbase = kg << 2;           // D rows = rbase..rbase+3

  // ---- one-time LDS preload (xor-swizzled rows; shared by the 4 waves) ----
  for (int c = tid; c < 16 * 96; c += 256) {
    int r = c / 96, kb = (c % 96) << 4;
    *(bf16x8*)(smem + SM_WB1 + r * 1536 + (kb ^ ((r & 7) << 4))) =
        *(const bf16x8*)(Wb1 + (size_t)(n0 + r) * KC + (kb >> 1));
  }
  for (int c = tid; c < 16 * 128; c += 256) {
    int r = c >> 7, kb = (c & 127) << 4;
    *(bf16x8*)(smem + SM_WB2 + r * 2048 + (kb ^ ((r & 7) << 4))) =
        *(const bf16x8*)(Wb2 + (size_t)(n0 + r) * BUu + (kb >> 1));
  }
  for (int c = tid; c < 24 * 128; c += 256) {
    int r = c >> 7, kb = (c & 127) << 4;
    *(bf16x8*)(smem + SM_WHD + r * 2048 + (kb ^ ((r & 7) << 4))) =
        *(const bf16x8*)(Whd + (size_t)(c0 + r) * BUu + (kb >> 1));
  }
  __syncthreads();

  // hoisted per-lane constants
  const float bias1 = bb1[n0 + row16];
  const float bias2 = bb2[n0 + row16];
  const short* hrow = hb + (b0 + row16) * Hh;
  const float* xbase = x + (size_t)(b0 + row16) * Tt * Ii;
  const short* z1row = z1 + (b0 + row16) * BUu;
  const short* z2row = z2 + (b0 + row16) * BUu;
  const int r3 = lane >> 2, iq = lane & 3;   // S3 epilogue mapping
  float bF1[2], bF2[2], bTT[2];
#pragma unroll
  for (int jj = 0; jj < 2; ++jj) {
    const int ig = ib + (iq << 1) + jj;
    bF1[jj] = bff1[ig];
    bF2[jj] = bff2[ig];
    bTT[jj] = bta[ig] + btb[ig];
  }
  short* T = (short*)(smem + SM_STAGE + wave * 1600);   // 16x16 bf16 transpose
  float* L3 = (float*)(smem + SM_STAGE + wave * 1600);  // 16x25 f32 S3 stage

  // x-part of S1 (kc 0..7, input-only): computed off the critical path.
  f32x4 xa0, xa1;
  auto xpart = [&](int t, f32x4& a0, f32x4& a1) {
    const float* xrow = xbase + (size_t)t * Ii;
    a0 = f32x4{0.f, 0.f, 0.f, 0.f};
    a1 = f32x4{0.f, 0.f, 0.f, 0.f};
#pragma unroll
    for (int kc = 0; kc < 8; ++kc) {
      const float* xp = xrow + (kc << 5) + (kg << 3);
      const f32x4 va = *(const f32x4*)xp;
      const f32x4 vb = *(const f32x4*)(xp + 4);
      bf16x8 a;
#pragma unroll
      for (int j = 0; j < 4; ++j) { a[j] = f2bf(va[j]); a[4 + j] = f2bf(vb[j]); }
      const bf16x8 b = *(const bf16x8*)(smem + SM_WB1 + row16 * 1536 + (((kc << 6) + kg16) ^ swzm));
      if (kc & 1) a1 = __builtin_amdgcn_mfma_f32_16x16x32_bf16(a, b, a1, 0, 0, 0);
      else        a0 = __builtin_amdgcn_mfma_f32_16x16x32_bf16(a, b, a0, 0, 0, 0);
    }
  };
  xpart(0, xa0, xa1);

#pragma unroll 1
  for (int t = 0; t < Tt; ++t) {
    if (t) bar_wait(flags, lane, 3u * t);   // h(t-1) visible at LLC

    // ========== S1: z1 = lecun(cat(x_t,h) @ Wb1^T + bb1), h-part K=512 ==========
    {
      bf16x8 ha[16];
#pragma unroll
      for (int kc = 0; kc < 16; ++kc)        // burst: all 32 8B loads in flight
        ha[kc] = ld16c(hrow + (kc << 5) + (kg << 3));
      f32x4 acc0 = xa0, acc1 = xa1;
#pragma unroll
      for (int kc = 0; kc < 16; ++kc) {
        const bf16x8 b = *(const bf16x8*)(smem + SM_WB1 + row16 * 1536 + ((((kc + 8) << 6) + kg16) ^ swzm));
        if (kc & 1) acc1 = __builtin_amdgcn_mfma_f32_16x16x32_bf16(ha[kc], b, acc1, 0, 0, 0);
        else        acc0 = __builtin_amdgcn_mfma_f32_16x16x32_bf16(ha[kc], b, acc0, 0, 0, 0);
      }
#pragma unroll
      for (int i = 0; i < 4; ++i)
        T[(rbase + i) * 16 + row16] = f2bf(lecun_act(acc0[i] + acc1[i] + bias1));
      __syncthreads();
      const int rr = lane >> 2, cc = (lane & 3) << 2;
      const u64 v = *(const u64*)(T + rr * 16 + cc);
      st8c(z1 + (size_t)(b0 + rr) * BUu + n0 + cc, v);
    }
    bar_arrive(flags, wg, tid, 3u * t + 1u);
    bar_wait(flags, lane, 3u * t + 1u);

    // ========== S2: z2 = lecun(z1 @ Wb2^T + bb2) ==========
    {
      bf16x8 za[32];
#pragma unroll
      for (int kc = 0; kc < 32; ++kc)        // burst: all 64 8B loads in flight
        za[kc] = ld16c(z1row + (kc << 5) + (kg << 3));
      f32x4 acc0 = {0.f, 0.f, 0.f, 0.f}, acc1 = {0.f, 0.f, 0.f, 0.f};
#pragma unroll
      for (int kc = 0; kc < 32; ++kc) {
        const bf16x8 b = *(const bf16x8*)(smem + SM_WB2 + row16 * 2048 + (((kc << 6) + kg16) ^ swzm));
        if (kc & 1) acc1 = __builtin_amdgcn_mfma_f32_16x16x32_bf16(za[kc], b, acc1, 0, 0, 0);
        else        acc0 = __builtin_amdgcn_mfma_f32_16x16x32_bf16(za[kc], b, acc0, 0, 0, 0);
      }
      __syncthreads();   // WAR: T was read at end of S1
#pragma unroll
      for (int i = 0; i < 4; ++i)
        T[(rbase + i) * 16 + row16] = f2bf(lecun_act(acc0[i] + acc1[i] + bias2));
      __syncthreads();
      const int rr = lane >> 2, cc = (lane & 3) << 2;
      const u64 v = *(const u64*)(T + rr * 16 + cc);
      st8c(z2 + (size_t)(b0 + rr) * BUu + n0 + cc, v);
    }
    bar_arrive(flags, wg, tid, 3u * t + 2u);
    bar_wait(flags, lane, 3u * t + 2u);

    // ========== S3: heads + gate + h_new + ys ==========
    {
      bf16x8 za[32];
#pragma unroll
      for (int kc = 0; kc < 32; ++kc)        // burst
        za[kc] = ld16c(z2row + (kc << 5) + (kg << 3));
      f32x4 p00 = {0.f,0.f,0.f,0.f}, p01 = {0.f,0.f,0.f,0.f};
      f32x4 p10 = {0.f,0.f,0.f,0.f}, p11 = {0.f,0.f,0.f,0.f};
#pragma unroll
      for (int kc = 0; kc < 32; ++kc) {
        const int kb = ((kc << 6) + kg16) ^ swzm;
        const bf16x8 w0 = *(const bf16x8*)(smem + SM_WHD + row16 * 2048 + kb);
        const bf16x8 w1 = *(const bf16x8*)(smem + SM_WHD + (16 + (row16 & 7)) * 2048 + kb);
        if (kc & 1) {
          p01 = __builtin_amdgcn_mfma_f32_16x16x32_bf16(za[kc], w0, p01, 0, 0, 0);
          p11 = __builtin_amdgcn_mfma_f32_16x16x32_bf16(za[kc], w1, p11, 0, 0, 0);
        } else {
          p00 = __builtin_amdgcn_mfma_f32_16x16x32_bf16(za[kc], w0, p00, 0, 0, 0);
          p10 = __builtin_amdgcn_mfma_f32_16x16x32_bf16(za[kc], w1, p10, 0, 0, 0);
        }
      }
      __syncthreads();   // WAR: T was read at end of S2
      // stage raw dots: L3[16 rows][24 cols(+pad)]; col lc = 3*i_local + head
#pragma unroll
      for (int i = 0; i < 4; ++i) {
        L3[(rbase + i) * 25 + row16] = p00[i] + p01[i];
        if (row16 < 8) L3[(rbase + i) * 25 + 16 + row16] = p10[i] + p11[i];
      }
      __syncthreads();
      unsigned hv = 0;
      float outv[2];
#pragma unroll
      for (int jj = 0; jj < 2; ++jj) {
        const int il = (iq << 1) + jj;     // local i 0..7
        const float a0 = L3[r3 * 25 + 3 * il + 0];
        const float a1 = L3[r3 * 25 + 3 * il + 1];
        const float a2 = L3[r3 * 25 + 3 * il + 2];
        const float ff1 = fast_tanh(a0 + bF1[jj]);
        const float ff2 = fast_tanh(a1 + bF2[jj]);
        const float tt  = fast_sig(a2 + bTT[jj]);
        const float hn = ff1 + tt * (ff2 - ff1);
        outv[jj] = hn;
        hv |= ((unsigned)(unsigned short)f2bf(hn)) << (16 * jj);
      }
      __hip_atomic_store((unsigned*)hb + (((b0 + r3) * Hh + ib + (iq << 1)) >> 1),
                         hv, __ATOMIC_RELAXED, __HIP_MEMORY_SCOPE_AGENT);
      float2 ov = { outv[0], outv[1] };
      *(float2*)(out + ((size_t)(b0 + r3) * Tt + t) * Hh + ib + (iq << 1)) = ov;
    }
    bar_arrive(flags, wg, tid, 3u * t + 3u);
    if (t + 1 < Tt) xpart(t + 1, xa0, xa1);   // hidden under straggler wait
  }
}

extern "C" void kernel_launch(void* const* d_in, const int* in_sizes, int n_in,
                              void* d_out, int out_size, void* d_ws, size_t ws_size,
                              hipStream_t stream) {
  const float* x    = (const float*)d_in[0];
  const float* wb1  = (const float*)d_in[1];
  const float* bb1  = (const float*)d_in[2];
  const float* wb2  = (const float*)d_in[3];
  const float* bb2  = (const float*)d_in[4];
  const float* wff1 = (const float*)d_in[5];
  const float* bff1 = (const float*)d_in[6];
  const float* wff2 = (const float*)d_in[7];
  const float* bff2 = (const float*)d_in[8];
  const float* wta  = (const float*)d_in[9];
  const float* bta  = (const float*)d_in[10];
  const float* wtb  = (const float*)d_in[11];
  const float* btb  = (const float*)d_in[12];
  unsigned char* ws = (unsigned char*)d_ws;

  const unsigned prep_items = 786432u + 1048576u + 1572864u + 32768u + 1024u;
  cfc_prep<<<(prep_items + 255u) / 256u, 256, 0, stream>>>(wb1, wb2, wff1, wff2, wta, wtb, ws);
  cfc_run<<<NWG, 256, SM_TOTAL, stream>>>(x, bb1, bb2, bff1, bff2, bta, btb, ws, (float*)d_out);
}